// Round 2
// baseline (5041.812 us; speedup 1.0000x reference)
//
#include <hip/hip_runtime.h>
#include <hip/hip_bf16.h>

#define NN    50000
#define NE    800000
#define INF   3
#define EMB   16
#define EDGEF 6
#define KW    128
#define OUTK  256   // EMB*EMB
#define NCONV 4

typedef unsigned short ushort_t;

__device__ __forceinline__ ushort_t f2bf(float f) {
    union { float f; unsigned u; } v; v.f = f;
    unsigned r = v.u + 0x7fffu + ((v.u >> 16) & 1u);   // round-to-nearest-even
    return (ushort_t)(r >> 16);
}
__device__ __forceinline__ float bf2f(ushort_t s) {
    union { float f; unsigned u; } v; v.u = ((unsigned)s) << 16;
    return v.f;
}

// ---------------- node embedding: h = x @ emb_w + emb_b ----------------
__global__ void embed_k(const float* __restrict__ x, const float* __restrict__ w,
                        const float* __restrict__ b, float* __restrict__ h) {
    int idx = blockIdx.x * blockDim.x + threadIdx.x;
    if (idx >= NN * EMB) return;
    int n = idx >> 4, o = idx & 15;
    float acc = b[o];
#pragma unroll
    for (int i = 0; i < INF; ++i) acc += x[n * INF + i] * w[i * EMB + o];
    h[idx] = acc;
}

// ---------------- in-degree counts ----------------
__global__ void count_k(const int* __restrict__ dst, float* __restrict__ counts) {
    int e = blockIdx.x * blockDim.x + threadIdx.x;
    if (e >= NE) return;
    atomicAdd(&counts[dst[e]], 1.0f);
}

// ============================ FULL tier ============================
// edge MLP: 6 -> 128 -> 128 -> 256, W stored bf16 (needs 410 MB ws)
__global__ __launch_bounds__(128) void mlp_k(
    const float* __restrict__ ea,
    const float* __restrict__ w1, const float* __restrict__ b1,
    const float* __restrict__ w2, const float* __restrict__ b2,
    const float* __restrict__ w3, const float* __restrict__ b3,
    ushort_t* __restrict__ W)
{
    __shared__ float eas[16 * EDGEF];
    __shared__ __align__(16) float e1s[16 * KW];
    __shared__ __align__(16) float e2s[16 * KW];

    const int t  = threadIdx.x;
    const long e0 = (long)blockIdx.x * 16;

    if (t < 16 * EDGEF) eas[t] = ea[e0 * EDGEF + t];
    __syncthreads();

    // stage 1
    {
        float wr[EDGEF];
#pragma unroll
        for (int k = 0; k < EDGEF; ++k) wr[k] = w1[k * KW + t];
        const float bb = b1[t];
#pragma unroll
        for (int e = 0; e < 16; ++e) {
            float acc = bb;
#pragma unroll
            for (int k = 0; k < EDGEF; ++k) acc += eas[e * EDGEF + k] * wr[k];
            e1s[e * KW + t] = fmaxf(acc, 0.0f);
        }
    }
    __syncthreads();

    const int g  = t & 31;
    const int eg = t >> 5;

    // stage 2
    {
        float acc[4][4];
#pragma unroll
        for (int e = 0; e < 4; ++e)
#pragma unroll
            for (int c = 0; c < 4; ++c) acc[e][c] = 0.f;

        const float4* w24  = (const float4*)w2;
        const float4* e1s4 = (const float4*)e1s;
        for (int k4 = 0; k4 < KW / 4; ++k4) {
            float wvf[4][4];
#pragma unroll
            for (int i = 0; i < 4; ++i) {
                float4 wv = w24[(k4 * 4 + i) * (KW / 4) + g];
                wvf[i][0] = wv.x; wvf[i][1] = wv.y; wvf[i][2] = wv.z; wvf[i][3] = wv.w;
            }
#pragma unroll
            for (int e = 0; e < 4; ++e) {
                float4 v = e1s4[(eg * 4 + e) * (KW / 4) + k4];
                float vv[4] = {v.x, v.y, v.z, v.w};
#pragma unroll
                for (int i = 0; i < 4; ++i)
#pragma unroll
                    for (int c = 0; c < 4; ++c)
                        acc[e][c] += vv[i] * wvf[i][c];
            }
        }
        float bb[4];
#pragma unroll
        for (int c = 0; c < 4; ++c) bb[c] = b2[g * 4 + c];
#pragma unroll
        for (int e = 0; e < 4; ++e) {
            float4 o;
            o.x = fmaxf(acc[e][0] + bb[0], 0.f);
            o.y = fmaxf(acc[e][1] + bb[1], 0.f);
            o.z = fmaxf(acc[e][2] + bb[2], 0.f);
            o.w = fmaxf(acc[e][3] + bb[3], 0.f);
            ((float4*)e2s)[(eg * 4 + e) * (KW / 4) + g] = o;
        }
    }
    __syncthreads();

    // stage 3 -> bf16 W
    {
        float acc[4][8];
#pragma unroll
        for (int e = 0; e < 4; ++e)
#pragma unroll
            for (int c = 0; c < 8; ++c) acc[e][c] = 0.f;

        const float4* w34  = (const float4*)w3;
        const float4* e2s4 = (const float4*)e2s;
        for (int k4 = 0; k4 < KW / 4; ++k4) {
            float wvf[4][8];
#pragma unroll
            for (int i = 0; i < 4; ++i) {
                float4 a = w34[(k4 * 4 + i) * (OUTK / 4) + g * 2];
                float4 b = w34[(k4 * 4 + i) * (OUTK / 4) + g * 2 + 1];
                wvf[i][0] = a.x; wvf[i][1] = a.y; wvf[i][2] = a.z; wvf[i][3] = a.w;
                wvf[i][4] = b.x; wvf[i][5] = b.y; wvf[i][6] = b.z; wvf[i][7] = b.w;
            }
#pragma unroll
            for (int e = 0; e < 4; ++e) {
                float4 v = e2s4[(eg * 4 + e) * (KW / 4) + k4];
                float vv[4] = {v.x, v.y, v.z, v.w};
#pragma unroll
                for (int i = 0; i < 4; ++i)
#pragma unroll
                    for (int c = 0; c < 8; ++c)
                        acc[e][c] += vv[i] * wvf[i][c];
            }
        }
        float bb[8];
#pragma unroll
        for (int c = 0; c < 8; ++c) bb[c] = b3[g * 8 + c];
#pragma unroll
        for (int e = 0; e < 4; ++e) {
            ushort_t tmp[8];
#pragma unroll
            for (int c = 0; c < 8; ++c) tmp[c] = f2bf(acc[e][c] + bb[c]);
            *(uint4*)(&W[(e0 + eg * 4 + e) * OUTK + g * 8]) = *(const uint4*)tmp;
        }
    }
}

// conv: msg = h[src] @ W[e], scatter-add (FULL tier)
__global__ __launch_bounds__(256) void conv_k(const int* __restrict__ ei,
        const ushort_t* __restrict__ W, const float* __restrict__ h,
        float* __restrict__ agg)
{
    long gid = (long)blockIdx.x * 256 + threadIdx.x;
    long e = gid >> 4;
    int  o = (int)(gid & 15);
    if (e >= NE) return;
    int s = ei[e];
    int d = ei[NE + e];
    const ushort_t* We = W + e * OUTK;
    const float*    hs = h + (long)s * EMB;
    float acc = 0.f;
#pragma unroll
    for (int i = 0; i < EMB; ++i)
        acc += hs[i] * bf2f(We[i * EMB + o]);
    atomicAdd(&agg[(long)d * EMB + o], acc);
}

// ============================ TINY tier ============================
// Fully fused: recompute edge MLP per conv iteration, multiply W (in regs)
// by gathered h[src], butterfly-reduce over i, scatter to agg. ~10 MB ws.
__global__ __launch_bounds__(128) void fused_k(
    const int* __restrict__ ei, const float* __restrict__ ea,
    const float* __restrict__ w1, const float* __restrict__ b1,
    const float* __restrict__ w2, const float* __restrict__ b2,
    const float* __restrict__ w3, const float* __restrict__ b3,
    const float* __restrict__ h, float* __restrict__ agg)
{
    __shared__ float eas[16 * EDGEF];
    __shared__ __align__(16) float e1s[16 * KW];
    __shared__ __align__(16) float e2s[16 * KW];
    __shared__ float hss[16][EMB];
    __shared__ int   sids[16], dids[16];

    const int t  = threadIdx.x;
    const long e0 = (long)blockIdx.x * 16;

    if (t < 16) { sids[t] = ei[e0 + t]; dids[t] = ei[NE + e0 + t]; }
    if (t < 16 * EDGEF) eas[t] = ea[e0 * EDGEF + t];
    __syncthreads();

    // gather h[src] tile: 16 edges x 16 feats (needs sids; synced below)
    {
        int e = t >> 3, i0 = (t & 7) * 2;
        float2 v = *(const float2*)&h[(long)sids[e] * EMB + i0];
        hss[e][i0] = v.x; hss[e][i0 + 1] = v.y;
    }

    // stage 1
    {
        float wr[EDGEF];
#pragma unroll
        for (int k = 0; k < EDGEF; ++k) wr[k] = w1[k * KW + t];
        const float bb = b1[t];
#pragma unroll
        for (int e = 0; e < 16; ++e) {
            float acc = bb;
#pragma unroll
            for (int k = 0; k < EDGEF; ++k) acc += eas[e * EDGEF + k] * wr[k];
            e1s[e * KW + t] = fmaxf(acc, 0.0f);
        }
    }
    __syncthreads();   // e1s + hss ready

    const int g  = t & 31;
    const int eg = t >> 5;

    // stage 2
    {
        float acc[4][4];
#pragma unroll
        for (int e = 0; e < 4; ++e)
#pragma unroll
            for (int c = 0; c < 4; ++c) acc[e][c] = 0.f;

        const float4* w24  = (const float4*)w2;
        const float4* e1s4 = (const float4*)e1s;
        for (int k4 = 0; k4 < KW / 4; ++k4) {
            float wvf[4][4];
#pragma unroll
            for (int i = 0; i < 4; ++i) {
                float4 wv = w24[(k4 * 4 + i) * (KW / 4) + g];
                wvf[i][0] = wv.x; wvf[i][1] = wv.y; wvf[i][2] = wv.z; wvf[i][3] = wv.w;
            }
#pragma unroll
            for (int e = 0; e < 4; ++e) {
                float4 v = e1s4[(eg * 4 + e) * (KW / 4) + k4];
                float vv[4] = {v.x, v.y, v.z, v.w};
#pragma unroll
                for (int i = 0; i < 4; ++i)
#pragma unroll
                    for (int c = 0; c < 4; ++c)
                        acc[e][c] += vv[i] * wvf[i][c];
            }
        }
        float bb[4];
#pragma unroll
        for (int c = 0; c < 4; ++c) bb[c] = b2[g * 4 + c];
#pragma unroll
        for (int e = 0; e < 4; ++e) {
            float4 o;
            o.x = fmaxf(acc[e][0] + bb[0], 0.f);
            o.y = fmaxf(acc[e][1] + bb[1], 0.f);
            o.z = fmaxf(acc[e][2] + bb[2], 0.f);
            o.w = fmaxf(acc[e][3] + bb[3], 0.f);
            ((float4*)e2s)[(eg * 4 + e) * (KW / 4) + g] = o;
        }
    }
    __syncthreads();

    // stage 3 (W in registers) fused with msg + scatter
    {
        float acc[4][8];
#pragma unroll
        for (int e = 0; e < 4; ++e)
#pragma unroll
            for (int c = 0; c < 8; ++c) acc[e][c] = 0.f;

        const float4* w34  = (const float4*)w3;
        const float4* e2s4 = (const float4*)e2s;
        for (int k4 = 0; k4 < KW / 4; ++k4) {
            float wvf[4][8];
#pragma unroll
            for (int i = 0; i < 4; ++i) {
                float4 a = w34[(k4 * 4 + i) * (OUTK / 4) + g * 2];
                float4 b = w34[(k4 * 4 + i) * (OUTK / 4) + g * 2 + 1];
                wvf[i][0] = a.x; wvf[i][1] = a.y; wvf[i][2] = a.z; wvf[i][3] = a.w;
                wvf[i][4] = b.x; wvf[i][5] = b.y; wvf[i][6] = b.z; wvf[i][7] = b.w;
            }
#pragma unroll
            for (int e = 0; e < 4; ++e) {
                float4 v = e2s4[(eg * 4 + e) * (KW / 4) + k4];
                float vv[4] = {v.x, v.y, v.z, v.w};
#pragma unroll
                for (int i = 0; i < 4; ++i)
#pragma unroll
                    for (int c = 0; c < 8; ++c)
                        acc[e][c] += vv[i] * wvf[i][c];
            }
        }
        float bb[8];
#pragma unroll
        for (int c = 0; c < 8; ++c) bb[c] = b3[g * 8 + c];

        // this thread's 8 cols of W[e] are (i = g>>1, o = (g&1)*8 + c)
        const int i_t = g >> 1;
        const int ob  = (g & 1) * 8;
#pragma unroll
        for (int el = 0; el < 4; ++el) {
            const int e = eg * 4 + el;
            const float hv = hss[e][i_t];
            float p[8];
#pragma unroll
            for (int c = 0; c < 8; ++c) p[c] = (acc[el][c] + bb[c]) * hv;
            // reduce over i: lanes differing in g bits 1..4 (same wave)
#pragma unroll
            for (int m = 2; m <= 16; m <<= 1)
#pragma unroll
                for (int c = 0; c < 8; ++c) p[c] += __shfl_xor(p[c], m, 64);
            if (i_t == 0) {
                const int d = dids[e];
#pragma unroll
                for (int c = 0; c < 8; ++c)
                    atomicAdd(&agg[(long)d * EMB + ob + c], p[c]);
            }
        }
    }
}

// ---------------- node update ----------------
__global__ void update_k(const float* __restrict__ agg, const float* __restrict__ counts,
        const float* __restrict__ h, const float* __restrict__ rw,
        const float* __restrict__ cb, float* __restrict__ hn)
{
    int idx = blockIdx.x * blockDim.x + threadIdx.x;
    if (idx >= NN * EMB) return;
    int n = idx >> 4, o = idx & 15;
    float acc = cb[o];
#pragma unroll
    for (int i = 0; i < EMB; ++i) acc += h[n * EMB + i] * rw[i * EMB + o];
    float a = agg[idx] / fmaxf(counts[n], 1.0f);
    hn[idx] = fmaxf(acc + a, 0.0f);
}

// ---------------- inverse embedding ----------------
__global__ void final_k(const float* __restrict__ h, const float* __restrict__ iw,
        const float* __restrict__ ib, float* __restrict__ out)
{
    int idx = blockIdx.x * blockDim.x + threadIdx.x;
    if (idx >= NN * INF) return;
    int n = idx / INF, f = idx % INF;
    float acc = ib[f];
#pragma unroll
    for (int i = 0; i < EMB; ++i) acc += h[n * EMB + i] * iw[i * INF + f];
    out[idx] = acc;
}

extern "C" void kernel_launch(void* const* d_in, const int* in_sizes, int n_in,
                              void* d_out, int out_size, void* d_ws, size_t ws_size,
                              hipStream_t stream)
{
    const float* x     = (const float*)d_in[0];
    const int*   ei    = (const int*)d_in[1];
    const float* ea    = (const float*)d_in[2];
    const float* emb_w = (const float*)d_in[3];
    const float* emb_b = (const float*)d_in[4];
    const float* k1w   = (const float*)d_in[5];
    const float* k1b   = (const float*)d_in[6];
    const float* k2w   = (const float*)d_in[7];
    const float* k2b   = (const float*)d_in[8];
    const float* k3w   = (const float*)d_in[9];
    const float* k3b   = (const float*)d_in[10];
    const float* rw    = (const float*)d_in[11];
    const float* cb    = (const float*)d_in[12];
    const float* iw    = (const float*)d_in[13];
    const float* ib    = (const float*)d_in[14];
    float* out = (float*)d_out;

    const size_t W_BYTES    = (size_t)NE * OUTK * sizeof(ushort_t); // 409.6 MB
    const size_t H_BYTES    = (size_t)NN * EMB * sizeof(float);     // 3.2 MB
    const size_t CNT_BYTES  = (size_t)NN * sizeof(float);
    const size_t FULL_NEED  = W_BYTES + 3 * H_BYTES + CNT_BYTES + 4096;

    const bool full = (ws_size >= FULL_NEED);

    char* ws = (char*)d_ws;
    size_t off = 0;
    ushort_t* W = nullptr;
    if (full) { W = (ushort_t*)(ws + off); off += W_BYTES; }
    float* h0     = (float*)(ws + off);   off += H_BYTES;
    float* h1     = (float*)(ws + off);   off += H_BYTES;
    float* agg    = (float*)(ws + off);   off += H_BYTES;
    float* counts = (float*)(ws + off);   off += CNT_BYTES;

    hipMemsetAsync(counts, 0, CNT_BYTES, stream);
    embed_k<<<(NN * EMB + 255) / 256, 256, 0, stream>>>(x, emb_w, emb_b, h0);
    count_k<<<(NE + 255) / 256, 256, 0, stream>>>(ei + NE, counts);

    if (full)
        mlp_k<<<NE / 16, 128, 0, stream>>>(ea, k1w, k1b, k2w, k2b, k3w, k3b, W);

    float* hc = h0;
    float* hn = h1;
    for (int it = 0; it < NCONV; ++it) {
        hipMemsetAsync(agg, 0, H_BYTES, stream);
        if (full)
            conv_k<<<(int)((long)NE * EMB / 256), 256, 0, stream>>>(ei, W, hc, agg);
        else
            fused_k<<<NE / 16, 128, 0, stream>>>(ei, ea, k1w, k1b, k2w, k2b,
                                                 k3w, k3b, hc, agg);
        update_k<<<(NN * EMB + 255) / 256, 256, 0, stream>>>(agg, counts, hc, rw, cb, hn);
        float* tmp = hc; hc = hn; hn = tmp;
    }
    final_k<<<(NN * INF + 255) / 256, 256, 0, stream>>>(hc, iw, ib, out);
}

// Round 6
// 822.577 us; speedup vs baseline: 6.1293x; 6.1293x over previous
//
#include <hip/hip_runtime.h>
#include <hip/hip_bf16.h>
#include <hip/hip_fp16.h>

#define NN    50000
#define NE    800000
#define INF   3
#define EMB   16
#define EDGEF 6
#define KW    128
#define OUTK  256   // EMB*EMB
#define NCONV 4

typedef unsigned int  u32;
typedef unsigned short u16;
typedef __attribute__((ext_vector_type(8))) _Float16 f16x8;
typedef __attribute__((ext_vector_type(4))) float f32x4;

union B128 { uint4 u; f16x8 h; };

__device__ __forceinline__ u16 f2h(float f) {
    union { _Float16 h; u16 u; } v; v.h = (_Float16)f;   // v_cvt_f16_f32, RNE
    return v.u;
}

// ---------------- node embedding ----------------
__global__ void embed_k(const float* __restrict__ x, const float* __restrict__ w,
                        const float* __restrict__ b, float* __restrict__ h) {
    int idx = blockIdx.x * blockDim.x + threadIdx.x;
    if (idx >= NN * EMB) return;
    int n = idx >> 4, o = idx & 15;
    float acc = b[o];
#pragma unroll
    for (int i = 0; i < INF; ++i) acc += x[n * INF + i] * w[i * EMB + o];
    h[idx] = acc;
}

// ---------------- in-degree counts ----------------
__global__ void count_k(const int* __restrict__ dst, float* __restrict__ counts) {
    int e = blockIdx.x * blockDim.x + threadIdx.x;
    if (e >= NE) return;
    atomicAdd(&counts[dst[e]], 1.0f);
}

// ---------------- weight prep: pack w1/w2/w3 into per-lane MFMA B-fragment order ----
// k-slot bijection (shared by A-pack and B-prep; any bijection is correct as long
// as both sides agree):
//   stage1 (no pairing):  k = (lane>>4)*8 + j          (k<6 real, else 0)
//   stage2/3 (paired):    k = ks*32 + (lane>>4)*4 + (j>>1) + 16*(j&1)
__global__ void prep_k(const float* __restrict__ w1, const float* __restrict__ w2,
                       const float* __restrict__ w3,
                       u16* __restrict__ w1p, u16* __restrict__ w2p, u16* __restrict__ w3p)
{
    int idx = blockIdx.x * 256 + threadIdx.x;
    if (idx < 4096) {                       // w1p [nt=8][lane=64][j=8]
        int j = idx & 7, l = (idx >> 3) & 63, nt = idx >> 9;
        int kk = (l >> 4) * 8 + j;
        int col = nt * 16 + (l & 15);
        w1p[idx] = (kk < EDGEF) ? f2h(w1[kk * KW + col]) : (u16)0;
    } else if (idx < 20480) {               // w2p [nt=8][ks=4][lane=64][j=8]
        int i2 = idx - 4096;
        int j = i2 & 7, l = (i2 >> 3) & 63, ks = (i2 >> 9) & 3, nt = i2 >> 11;
        int kk = ks * 32 + ((l >> 4) * 4) + (j >> 1) + 16 * (j & 1);
        int col = nt * 16 + (l & 15);
        w2p[i2] = f2h(w2[kk * KW + col]);
    } else if (idx < 53248) {               // w3p [ct=16][ks=4][lane=64][j=8]
        int i3 = idx - 20480;
        int j = i3 & 7, l = (i3 >> 3) & 63, ks = (i3 >> 9) & 3, ct = i3 >> 11;
        int kk = ks * 32 + ((l >> 4) * 4) + (j >> 1) + 16 * (j & 1);
        int col = ct * 16 + (l & 15);
        w3p[i3] = f2h(w3[kk * OUTK + col]);
    }
}

// ---------------- fused MFMA conv kernel (fp16 operands, fp32 accum) ----------------
// 64 edges/block, 128 threads = 2 waves; each wave owns 32 edges = 2 M-tiles.
// Wave-local edge el (0..31) maps to block edge wid*32 + el.
// stage1: ea[16x6->pad32] @ w1 -> e1[16x128]
// stage2: e1 @ w2 -> e2[16x128]
// stage3: e2 @ w3 -> W[16x256]; N-tile ct == i index, so msg folds lane-locally:
//         msg[e][o] += (acc[r] + b3[ct*16+o]) * h[src[e]][ct]; then 8 atomics/thread.
// LDS e1/e2 share one wave-private buffer [32][64 u32], XOR-swizzled (bank fix).
__global__ __launch_bounds__(128) void gno_k(
    const int* __restrict__ ei, const float* __restrict__ ea,
    const uint4* __restrict__ w1p, const float* __restrict__ b1,
    const uint4* __restrict__ w2p, const float* __restrict__ b2,
    const uint4* __restrict__ w3p, const float* __restrict__ b3,
    const float* __restrict__ h, float* __restrict__ agg)
{
    __shared__ float eas[64 * EDGEF];
    __shared__ int   dids[64];
    __shared__ float hsst[16 * 64];       // transposed gather: hsst[i][edge]
    __shared__ u32   e12[2 * 32 * 64];    // per-wave act buffer

    const int t  = threadIdx.x;
    const long e0 = (long)blockIdx.x * 64;

    for (int k = t; k < 64 * EDGEF; k += 128) eas[k] = ea[e0 * EDGEF + k];
    if (t < 64) dids[t] = ei[NE + e0 + t];
    {
        int edge = t >> 1, i0 = (t & 1) * 8;
        int sid = ei[e0 + edge];
        f32x4 v0 = *(const f32x4*)&h[(long)sid * EMB + i0];
        f32x4 v1 = *(const f32x4*)&h[(long)sid * EMB + i0 + 4];
#pragma unroll
        for (int j = 0; j < 4; ++j) {
            hsst[(i0 + j) * 64 + edge]     = v0[j];
            hsst[(i0 + 4 + j) * 64 + edge] = v1[j];
        }
    }
    __syncthreads();

    const int wid = t >> 6, lane = t & 63, o = lane & 15, g = lane >> 4;
    u32* eb = &e12[wid * 2048];

    // ---- stage 1: A-frag from ea (k = g*8+j, real k<6) ----
    // BUGFIX r4: edge is wave-local -> block edge = wid*32 + m*16 + o
    f16x8 a1[2];
#pragma unroll
    for (int m = 0; m < 2; ++m) {
        f16x8 a = {0, 0, 0, 0, 0, 0, 0, 0};
        if (g == 0) {
#pragma unroll
            for (int j = 0; j < EDGEF; ++j)
                a[j] = (_Float16)eas[(wid * 32 + m * 16 + o) * EDGEF + j];
        }
        a1[m] = a;
    }
    for (int p = 0; p < 4; ++p) {
        f32x4 acc[2][2] = {};
#pragma unroll
        for (int nth = 0; nth < 2; ++nth) {
            B128 bb; bb.u = w1p[(p * 2 + nth) * 64 + lane];
#pragma unroll
            for (int m = 0; m < 2; ++m)
                acc[m][nth] = __builtin_amdgcn_mfma_f32_16x16x32_f16(a1[m], bb.h, acc[m][nth], 0, 0, 0);
        }
        float blo = b1[(p * 2) * 16 + o], bhi = b1[(p * 2 + 1) * 16 + o];
#pragma unroll
        for (int m = 0; m < 2; ++m)
#pragma unroll
            for (int r = 0; r < 4; ++r) {
                float lo = fmaxf(acc[m][0][r] + blo, 0.f);
                float hi = fmaxf(acc[m][1][r] + bhi, 0.f);
                int el = m * 16 + g * 4 + r;
                eb[(el * 64 + p * 16 + o) ^ ((el & 7) << 2)] =
                    (u32)f2h(lo) | ((u32)f2h(hi) << 16);
            }
    }
    __syncthreads();

    // ---- stage 2: e1 @ w2 ----
    f16x8 a2[2][4];
#pragma unroll
    for (int m = 0; m < 2; ++m) {
        int el = m * 16 + o;
#pragma unroll
        for (int ks = 0; ks < 4; ++ks) {
            B128 v; v.u = *(const uint4*)&eb[(el * 64 + ks * 16 + g * 4) ^ ((el & 7) << 2)];
            a2[m][ks] = v.h;
        }
    }
    __syncthreads();   // all e1 frags in regs before e2 overwrites the buffer
    for (int p = 0; p < 4; ++p) {
        f32x4 acc[2][2] = {};
#pragma unroll
        for (int ks = 0; ks < 4; ++ks)
#pragma unroll
            for (int nth = 0; nth < 2; ++nth) {
                B128 bb; bb.u = w2p[((p * 2 + nth) * 4 + ks) * 64 + lane];
#pragma unroll
                for (int m = 0; m < 2; ++m)
                    acc[m][nth] = __builtin_amdgcn_mfma_f32_16x16x32_f16(a2[m][ks], bb.h, acc[m][nth], 0, 0, 0);
            }
        float blo = b2[(p * 2) * 16 + o], bhi = b2[(p * 2 + 1) * 16 + o];
#pragma unroll
        for (int m = 0; m < 2; ++m)
#pragma unroll
            for (int r = 0; r < 4; ++r) {
                float lo = fmaxf(acc[m][0][r] + blo, 0.f);
                float hi = fmaxf(acc[m][1][r] + bhi, 0.f);
                int el = m * 16 + g * 4 + r;
                eb[(el * 64 + p * 16 + o) ^ ((el & 7) << 2)] =
                    (u32)f2h(lo) | ((u32)f2h(hi) << 16);
            }
    }
    __syncthreads();

    // ---- stage 3: e2 @ w3, fold msg, scatter ----
    f16x8 a3[2][4];
#pragma unroll
    for (int m = 0; m < 2; ++m) {
        int el = m * 16 + o;
#pragma unroll
        for (int ks = 0; ks < 4; ++ks) {
            B128 v; v.u = *(const uint4*)&eb[(el * 64 + ks * 16 + g * 4) ^ ((el & 7) << 2)];
            a3[m][ks] = v.h;
        }
    }
    f32x4 msg[2] = {};
    for (int ct = 0; ct < 16; ++ct) {
        f32x4 acc[2] = {};
#pragma unroll
        for (int ks = 0; ks < 4; ++ks) {
            B128 bb; bb.u = w3p[(ct * 4 + ks) * 64 + lane];
#pragma unroll
            for (int m = 0; m < 2; ++m)
                acc[m] = __builtin_amdgcn_mfma_f32_16x16x32_f16(a3[m][ks], bb.h, acc[m], 0, 0, 0);
        }
        float b3v = b3[ct * 16 + o];
#pragma unroll
        for (int m = 0; m < 2; ++m) {
            f32x4 hv = *(const f32x4*)&hsst[ct * 64 + wid * 32 + m * 16 + g * 4];
#pragma unroll
            for (int r = 0; r < 4; ++r)
                msg[m][r] += (acc[m][r] + b3v) * hv[r];
        }
    }
#pragma unroll
    for (int m = 0; m < 2; ++m)
#pragma unroll
        for (int r = 0; r < 4; ++r) {
            int elb = wid * 32 + m * 16 + g * 4 + r;
            atomicAdd(&agg[(long)dids[elb] * EMB + o], msg[m][r]);
        }
}

// ---------------- node update ----------------
__global__ void update_k(const float* __restrict__ agg, const float* __restrict__ counts,
        const float* __restrict__ h, const float* __restrict__ rw,
        const float* __restrict__ cb, float* __restrict__ hn)
{
    int idx = blockIdx.x * blockDim.x + threadIdx.x;
    if (idx >= NN * EMB) return;
    int n = idx >> 4, o = idx & 15;
    float acc = cb[o];
#pragma unroll
    for (int i = 0; i < EMB; ++i) acc += h[n * EMB + i] * rw[i * EMB + o];
    float a = agg[idx] / fmaxf(counts[n], 1.0f);
    hn[idx] = fmaxf(acc + a, 0.0f);
}

// ---------------- inverse embedding ----------------
__global__ void final_k(const float* __restrict__ h, const float* __restrict__ iw,
        const float* __restrict__ ib, float* __restrict__ out)
{
    int idx = blockIdx.x * blockDim.x + threadIdx.x;
    if (idx >= NN * INF) return;
    int n = idx / INF, f = idx % INF;
    float acc = ib[f];
#pragma unroll
    for (int i = 0; i < EMB; ++i) acc += h[n * EMB + i] * iw[i * INF + f];
    out[idx] = acc;
}

extern "C" void kernel_launch(void* const* d_in, const int* in_sizes, int n_in,
                              void* d_out, int out_size, void* d_ws, size_t ws_size,
                              hipStream_t stream)
{
    const float* x     = (const float*)d_in[0];
    const int*   ei    = (const int*)d_in[1];
    const float* ea    = (const float*)d_in[2];
    const float* emb_w = (const float*)d_in[3];
    const float* emb_b = (const float*)d_in[4];
    const float* k1w   = (const float*)d_in[5];
    const float* k1b   = (const float*)d_in[6];
    const float* k2w   = (const float*)d_in[7];
    const float* k2b   = (const float*)d_in[8];
    const float* k3w   = (const float*)d_in[9];
    const float* k3b   = (const float*)d_in[10];
    const float* rw    = (const float*)d_in[11];
    const float* cb    = (const float*)d_in[12];
    const float* iw    = (const float*)d_in[13];
    const float* ib    = (const float*)d_in[14];
    float* out = (float*)d_out;

    char* ws = (char*)d_ws;
    u16* w1p = (u16*)(ws);                    //  8 KB  (4096)
    u16* w2p = (u16*)(ws + 8192);             // 32 KB  (16384)
    u16* w3p = (u16*)(ws + 40960);            // 64 KB  (32768)
    size_t off = 106496;                      // 256B-aligned
    float* h0     = (float*)(ws + off); off += (size_t)NN * EMB * sizeof(float);
    float* h1     = (float*)(ws + off); off += (size_t)NN * EMB * sizeof(float);
    float* agg    = (float*)(ws + off); off += (size_t)NN * EMB * sizeof(float);
    float* counts = (float*)(ws + off); off += (size_t)NN * sizeof(float);

    hipMemsetAsync(counts, 0, (size_t)NN * sizeof(float), stream);
    prep_k<<<208, 256, 0, stream>>>(k1w, k2w, k3w, w1p, w2p, w3p);
    embed_k<<<(NN * EMB + 255) / 256, 256, 0, stream>>>(x, emb_w, emb_b, h0);
    count_k<<<(NE + 255) / 256, 256, 0, stream>>>(ei + NE, counts);

    float* hc = h0;
    float* hn = h1;
    for (int it = 0; it < NCONV; ++it) {
        hipMemsetAsync(agg, 0, (size_t)NN * EMB * sizeof(float), stream);
        gno_k<<<NE / 64, 128, 0, stream>>>(ei, ea,
                (const uint4*)w1p, k1b, (const uint4*)w2p, k2b,
                (const uint4*)w3p, k3b, hc, agg);
        update_k<<<(NN * EMB + 255) / 256, 256, 0, stream>>>(agg, counts, hc, rw, cb, hn);
        float* tmp = hc; hc = hn; hn = tmp;
    }
    final_k<<<(NN * INF + 255) / 256, 256, 0, stream>>>(hc, iw, ib, out);
}

// Round 7
// 779.962 us; speedup vs baseline: 6.4642x; 1.0546x over previous
//
#include <hip/hip_runtime.h>
#include <hip/hip_bf16.h>
#include <hip/hip_fp16.h>

#define NN    50000
#define NE    800000
#define INF   3
#define EMB   16
#define EDGEF 6
#define KW    128
#define OUTK  256   // EMB*EMB
#define NCONV 4

typedef unsigned int  u32;
typedef unsigned short u16;
typedef __attribute__((ext_vector_type(8))) _Float16 f16x8;
typedef __attribute__((ext_vector_type(4))) float f32x4;

union B128 { uint4 u; f16x8 h; };
union H16  { u16 u; _Float16 h; };

__device__ __forceinline__ u16 f2h(float f) {
    union { _Float16 h; u16 u; } v; v.h = (_Float16)f;   // v_cvt_f16_f32, RNE
    return v.u;
}

// ---------------- node embedding ----------------
__global__ void embed_k(const float* __restrict__ x, const float* __restrict__ w,
                        const float* __restrict__ b, float* __restrict__ h) {
    int idx = blockIdx.x * blockDim.x + threadIdx.x;
    if (idx >= NN * EMB) return;
    int n = idx >> 4, o = idx & 15;
    float acc = b[o];
#pragma unroll
    for (int i = 0; i < INF; ++i) acc += x[n * INF + i] * w[i * EMB + o];
    h[idx] = acc;
}

// ---------------- in-degree counts ----------------
__global__ void count_k(const int* __restrict__ dst, float* __restrict__ counts) {
    int e = blockIdx.x * blockDim.x + threadIdx.x;
    if (e >= NE) return;
    atomicAdd(&counts[dst[e]], 1.0f);
}

// ---------------- weight prep: pack w1/w2/w3 into per-lane MFMA B-fragment order ----
// k-slot bijection (shared by A-pack and B-prep):
//   stage1 (no pairing):  k = (lane>>4)*8 + j          (k<6 real, else 0)
//   stage2/3 (paired):    k = ks*32 + (lane>>4)*4 + (j>>1) + 16*(j&1)
__global__ void prep_k(const float* __restrict__ w1, const float* __restrict__ w2,
                       const float* __restrict__ w3,
                       u16* __restrict__ w1p, u16* __restrict__ w2p, u16* __restrict__ w3p)
{
    int idx = blockIdx.x * 256 + threadIdx.x;
    if (idx < 4096) {                       // w1p [nt=8][lane=64][j=8]
        int j = idx & 7, l = (idx >> 3) & 63, nt = idx >> 9;
        int kk = (l >> 4) * 8 + j;
        int col = nt * 16 + (l & 15);
        w1p[idx] = (kk < EDGEF) ? f2h(w1[kk * KW + col]) : (u16)0;
    } else if (idx < 20480) {               // w2p [nt=8][ks=4][lane=64][j=8]
        int i2 = idx - 4096;
        int j = i2 & 7, l = (i2 >> 3) & 63, ks = (i2 >> 9) & 3, nt = i2 >> 11;
        int kk = ks * 32 + ((l >> 4) * 4) + (j >> 1) + 16 * (j & 1);
        int col = nt * 16 + (l & 15);
        w2p[i2] = f2h(w2[kk * KW + col]);
    } else if (idx < 53248) {               // w3p [ct=16][ks=4][lane=64][j=8]
        int i3 = idx - 20480;
        int j = i3 & 7, l = (i3 >> 3) & 63, ks = (i3 >> 9) & 3, ct = i3 >> 11;
        int kk = ks * 32 + ((l >> 4) * 4) + (j >> 1) + 16 * (j & 1);
        int col = ct * 16 + (l & 15);
        w3p[i3] = f2h(w3[kk * OUTK + col]);
    }
}

// ---------------- fused MFMA conv kernel (fp16 operands, fp32 accum) ----------------
// 64 edges/block, 128 threads = 2 waves; each wave owns 32 edges = 2 M-tiles.
// R7: single barrier (e12 is wave-private; eas/dids/hsst read-only after it),
//     unrolled p/ct loops + VGPR cap 128 for deep load pipelining, eas in fp16.
__global__ __launch_bounds__(128, 4) void gno_k(
    const int* __restrict__ ei, const float* __restrict__ ea,
    const uint4* __restrict__ w1p, const float* __restrict__ b1,
    const uint4* __restrict__ w2p, const float* __restrict__ b2,
    const uint4* __restrict__ w3p, const float* __restrict__ b3,
    const float* __restrict__ h, float* __restrict__ agg)
{
    __shared__ u16   eas[64 * EDGEF];     // fp16 edge attrs
    __shared__ int   dids[64];
    __shared__ float hsst[16 * 64];       // transposed gather: hsst[i][edge]
    __shared__ u32   e12[2 * 32 * 64];    // per-wave act buffer (XOR-swizzled)

    const int t  = threadIdx.x;
    const long e0 = (long)blockIdx.x * 64;

    for (int k = t; k < 64 * EDGEF; k += 128) eas[k] = f2h(ea[e0 * EDGEF + k]);
    if (t < 64) dids[t] = ei[NE + e0 + t];
    {
        int edge = t >> 1, i0 = (t & 1) * 8;
        int sid = ei[e0 + edge];
        f32x4 v0 = *(const f32x4*)&h[(long)sid * EMB + i0];
        f32x4 v1 = *(const f32x4*)&h[(long)sid * EMB + i0 + 4];
#pragma unroll
        for (int j = 0; j < 4; ++j) {
            hsst[(i0 + j) * 64 + edge]     = v0[j];
            hsst[(i0 + 4 + j) * 64 + edge] = v1[j];
        }
    }
    __syncthreads();   // the ONLY barrier: eas/dids/hsst are read-only below

    const int wid = t >> 6, lane = t & 63, o = lane & 15, g = lane >> 4;
    u32* eb = &e12[wid * 2048];

    // ---- stage 1: A-frag from ea (k = g*8+j, real k<6) ----
    f16x8 a1[2];
#pragma unroll
    for (int m = 0; m < 2; ++m) {
        f16x8 a = {0, 0, 0, 0, 0, 0, 0, 0};
        if (g == 0) {
#pragma unroll
            for (int j = 0; j < EDGEF; ++j) {
                H16 v; v.u = eas[(wid * 32 + m * 16 + o) * EDGEF + j];
                a[j] = v.h;
            }
        }
        a1[m] = a;
    }
#pragma unroll
    for (int p = 0; p < 4; ++p) {
        f32x4 acc[2][2] = {};
#pragma unroll
        for (int nth = 0; nth < 2; ++nth) {
            B128 bb; bb.u = w1p[(p * 2 + nth) * 64 + lane];
#pragma unroll
            for (int m = 0; m < 2; ++m)
                acc[m][nth] = __builtin_amdgcn_mfma_f32_16x16x32_f16(a1[m], bb.h, acc[m][nth], 0, 0, 0);
        }
        float blo = b1[(p * 2) * 16 + o], bhi = b1[(p * 2 + 1) * 16 + o];
#pragma unroll
        for (int m = 0; m < 2; ++m)
#pragma unroll
            for (int r = 0; r < 4; ++r) {
                float lo = fmaxf(acc[m][0][r] + blo, 0.f);
                float hi = fmaxf(acc[m][1][r] + bhi, 0.f);
                int el = m * 16 + g * 4 + r;
                eb[(el * 64 + p * 16 + o) ^ ((el & 7) << 2)] =
                    (u32)f2h(lo) | ((u32)f2h(hi) << 16);
            }
    }
    // no barrier: eb is wave-private, DS ops in-order within a wave

    // ---- stage 2: e1 @ w2 ----
    f16x8 a2[2][4];
#pragma unroll
    for (int m = 0; m < 2; ++m) {
        int el = m * 16 + o;
#pragma unroll
        for (int ks = 0; ks < 4; ++ks) {
            B128 v; v.u = *(const uint4*)&eb[(el * 64 + ks * 16 + g * 4) ^ ((el & 7) << 2)];
            a2[m][ks] = v.h;
        }
    }
#pragma unroll
    for (int p = 0; p < 4; ++p) {
        f32x4 acc[2][2] = {};
#pragma unroll
        for (int ks = 0; ks < 4; ++ks)
#pragma unroll
            for (int nth = 0; nth < 2; ++nth) {
                B128 bb; bb.u = w2p[((p * 2 + nth) * 4 + ks) * 64 + lane];
#pragma unroll
                for (int m = 0; m < 2; ++m)
                    acc[m][nth] = __builtin_amdgcn_mfma_f32_16x16x32_f16(a2[m][ks], bb.h, acc[m][nth], 0, 0, 0);
            }
        float blo = b2[(p * 2) * 16 + o], bhi = b2[(p * 2 + 1) * 16 + o];
#pragma unroll
        for (int m = 0; m < 2; ++m)
#pragma unroll
            for (int r = 0; r < 4; ++r) {
                float lo = fmaxf(acc[m][0][r] + blo, 0.f);
                float hi = fmaxf(acc[m][1][r] + bhi, 0.f);
                int el = m * 16 + g * 4 + r;
                eb[(el * 64 + p * 16 + o) ^ ((el & 7) << 2)] =
                    (u32)f2h(lo) | ((u32)f2h(hi) << 16);
            }
    }

    // ---- stage 3: e2 @ w3, fold msg, scatter ----
    f16x8 a3[2][4];
#pragma unroll
    for (int m = 0; m < 2; ++m) {
        int el = m * 16 + o;
#pragma unroll
        for (int ks = 0; ks < 4; ++ks) {
            B128 v; v.u = *(const uint4*)&eb[(el * 64 + ks * 16 + g * 4) ^ ((el & 7) << 2)];
            a3[m][ks] = v.h;
        }
    }
    f32x4 msg[2] = {};
#pragma unroll
    for (int ct = 0; ct < 16; ++ct) {
        f32x4 acc[2] = {};
#pragma unroll
        for (int ks = 0; ks < 4; ++ks) {
            B128 bb; bb.u = w3p[(ct * 4 + ks) * 64 + lane];
#pragma unroll
            for (int m = 0; m < 2; ++m)
                acc[m] = __builtin_amdgcn_mfma_f32_16x16x32_f16(a3[m][ks], bb.h, acc[m], 0, 0, 0);
        }
        float b3v = b3[ct * 16 + o];
#pragma unroll
        for (int m = 0; m < 2; ++m) {
            f32x4 hv = *(const f32x4*)&hsst[ct * 64 + wid * 32 + m * 16 + g * 4];
#pragma unroll
            for (int r = 0; r < 4; ++r)
                msg[m][r] += (acc[m][r] + b3v) * hv[r];
        }
    }
#pragma unroll
    for (int m = 0; m < 2; ++m)
#pragma unroll
        for (int r = 0; r < 4; ++r) {
            int elb = wid * 32 + m * 16 + g * 4 + r;
            atomicAdd(&agg[(long)dids[elb] * EMB + o], msg[m][r]);
        }
}

// ---------------- node update ----------------
__global__ void update_k(const float* __restrict__ agg, const float* __restrict__ counts,
        const float* __restrict__ h, const float* __restrict__ rw,
        const float* __restrict__ cb, float* __restrict__ hn)
{
    int idx = blockIdx.x * blockDim.x + threadIdx.x;
    if (idx >= NN * EMB) return;
    int n = idx >> 4, o = idx & 15;
    float acc = cb[o];
#pragma unroll
    for (int i = 0; i < EMB; ++i) acc += h[n * EMB + i] * rw[i * EMB + o];
    float a = agg[idx] / fmaxf(counts[n], 1.0f);
    hn[idx] = fmaxf(acc + a, 0.0f);
}

// ---------------- inverse embedding ----------------
__global__ void final_k(const float* __restrict__ h, const float* __restrict__ iw,
        const float* __restrict__ ib, float* __restrict__ out)
{
    int idx = blockIdx.x * blockDim.x + threadIdx.x;
    if (idx >= NN * INF) return;
    int n = idx / INF, f = idx % INF;
    float acc = ib[f];
#pragma unroll
    for (int i = 0; i < EMB; ++i) acc += h[n * EMB + i] * iw[i * INF + f];
    out[idx] = acc;
}

extern "C" void kernel_launch(void* const* d_in, const int* in_sizes, int n_in,
                              void* d_out, int out_size, void* d_ws, size_t ws_size,
                              hipStream_t stream)
{
    const float* x     = (const float*)d_in[0];
    const int*   ei    = (const int*)d_in[1];
    const float* ea    = (const float*)d_in[2];
    const float* emb_w = (const float*)d_in[3];
    const float* emb_b = (const float*)d_in[4];
    const float* k1w   = (const float*)d_in[5];
    const float* k1b   = (const float*)d_in[6];
    const float* k2w   = (const float*)d_in[7];
    const float* k2b   = (const float*)d_in[8];
    const float* k3w   = (const float*)d_in[9];
    const float* k3b   = (const float*)d_in[10];
    const float* rw    = (const float*)d_in[11];
    const float* cb    = (const float*)d_in[12];
    const float* iw    = (const float*)d_in[13];
    const float* ib    = (const float*)d_in[14];
    float* out = (float*)d_out;

    char* ws = (char*)d_ws;
    u16* w1p = (u16*)(ws);                    //  8 KB  (4096)
    u16* w2p = (u16*)(ws + 8192);             // 32 KB  (16384)
    u16* w3p = (u16*)(ws + 40960);            // 64 KB  (32768)
    size_t off = 106496;                      // 256B-aligned
    float* h0     = (float*)(ws + off); off += (size_t)NN * EMB * sizeof(float);
    float* h1     = (float*)(ws + off); off += (size_t)NN * EMB * sizeof(float);
    float* agg    = (float*)(ws + off); off += (size_t)NN * EMB * sizeof(float);
    float* counts = (float*)(ws + off); off += (size_t)NN * sizeof(float);

    hipMemsetAsync(counts, 0, (size_t)NN * sizeof(float), stream);
    prep_k<<<208, 256, 0, stream>>>(k1w, k2w, k3w, w1p, w2p, w3p);
    embed_k<<<(NN * EMB + 255) / 256, 256, 0, stream>>>(x, emb_w, emb_b, h0);
    count_k<<<(NE + 255) / 256, 256, 0, stream>>>(ei + NE, counts);

    float* hc = h0;
    float* hn = h1;
    for (int it = 0; it < NCONV; ++it) {
        hipMemsetAsync(agg, 0, (size_t)NN * EMB * sizeof(float), stream);
        gno_k<<<NE / 64, 128, 0, stream>>>(ei, ea,
                (const uint4*)w1p, k1b, (const uint4*)w2p, k2b,
                (const uint4*)w3p, k3b, hc, agg);
        update_k<<<(NN * EMB + 255) / 256, 256, 0, stream>>>(agg, counts, hc, rw, cb, hn);
        float* tmp = hc; hc = hn; hn = tmp;
    }
    final_k<<<(NN * INF + 255) / 256, 256, 0, stream>>>(hc, iw, ib, out);
}